// Round 1
// baseline (6998.217 us; speedup 1.0000x reference)
//
#include <hip/hip_runtime.h>
#include <cstdint>

#define B_ 64
#define L_ 512
#define H_ 1024
#define D_ 2048

// ---------------- s[b,h] = sum_l h_state[b,l,h] ----------------
__global__ __launch_bounds__(256) void k_s(const float* __restrict__ h, float* __restrict__ s) {
    int t = blockIdx.x * 256 + threadIdx.x;            // 65536 threads
    int b = t >> 10, hh = t & 1023;
    const float* p = h + ((size_t)b * L_) * H_ + hh;
    float acc = 0.f;
#pragma unroll 8
    for (int l = 0; l < L_; ++l) acc += p[(size_t)l * H_];
    s[t] = acc;
}

// ---------------- cnt0[b] = #(mask[b,l]==0) ----------------
__global__ __launch_bounds__(256) void k_cnt(const int* __restrict__ mask, float* __restrict__ cnt0) {
    int b = blockIdx.x, t = threadIdx.x;
    int c = 0;
    for (int l = t; l < L_; l += 256) c += (mask[b * L_ + l] == 0);
    __shared__ int sh[256];
    sh[t] = c; __syncthreads();
    for (int s2 = 128; s2 > 0; s2 >>= 1) { if (t < s2) sh[t] += sh[t + s2]; __syncthreads(); }
    if (t == 0) cnt0[b] = (float)sh[0];
}

// ---------------- t2[b,e] = s[b,:]@W_s[e,:] + b_a[e] + b_s[e] ----------------
// small GEMM: M=64(b), N=2048(e), K=1024(h). Tile 64x64, BK=16, 256 thr, 4x4 micro.
__global__ __launch_bounds__(256) void k_t2(const float* __restrict__ s, const float* __restrict__ Ws,
                                            const float* __restrict__ ba, const float* __restrict__ bs,
                                            float* __restrict__ t2) {
    __shared__ float As[16][64];
    __shared__ float Bs[16][64];
    int n0 = blockIdx.x * 64;
    int tid = threadIdx.x;
    int tx = tid & 15, ty = tid >> 4;
    int r = tid >> 2, q = tid & 3;
    float acc[4][4] = {};
    for (int k0 = 0; k0 < H_; k0 += 16) {
        float4 av = *(const float4*)(s + (size_t)r * H_ + k0 + q * 4);
        float4 bv = *(const float4*)(Ws + (size_t)(n0 + r) * H_ + k0 + q * 4);
        __syncthreads();
        As[q*4+0][r] = av.x; As[q*4+1][r] = av.y; As[q*4+2][r] = av.z; As[q*4+3][r] = av.w;
        Bs[q*4+0][r] = bv.x; Bs[q*4+1][r] = bv.y; Bs[q*4+2][r] = bv.z; Bs[q*4+3][r] = bv.w;
        __syncthreads();
#pragma unroll
        for (int kk = 0; kk < 16; ++kk) {
            float a_[4], b_[4];
            *(float4*)&a_[0] = *(const float4*)&As[kk][ty * 4];
            *(float4*)&b_[0] = *(const float4*)&Bs[kk][tx * 4];
#pragma unroll
            for (int i = 0; i < 4; ++i)
#pragma unroll
                for (int j = 0; j < 4; ++j) acc[i][j] += a_[i] * b_[j];
        }
    }
#pragma unroll
    for (int i = 0; i < 4; ++i)
#pragma unroll
        for (int j = 0; j < 4; ++j) {
            int bb = ty * 4 + i, e = n0 + tx * 4 + j;
            t2[(size_t)bb * D_ + e] = acc[i][j] + ba[e] + bs[e];
        }
}

// ---------------- main fused GEMM passes ----------------
// C[row,e] = a[row,:] @ W_a[e,:]  (B^T layout), row = b*512+l
// pass 1: rowsum[row] += sum_e exp(tanh(C+t2))
// pass 2: out[b,e]    += sum_rows mask ? exp(tanh(C+t2))/rowsum[row] : 0
#define BM 128
#define BN 128
#define BK 16
__global__ __launch_bounds__(256) void k_pass(
    const float* __restrict__ hs, const float* __restrict__ xx,
    const float* __restrict__ Wa, const float* __restrict__ t2,
    const int* __restrict__ mask, float* __restrict__ rowsum,
    float* __restrict__ out, int pass) {
    __shared__ float As[BK][BM];
    __shared__ float Bs[BK][BN];
    __shared__ float red[BM];
    int tid = threadIdx.x;
    int tx = tid & 15, ty = tid >> 4;
    int n0 = blockIdx.x * BN;
    int row0 = blockIdx.y * BM;
    int gb = row0 >> 9;       // 512 rows per batch; BM=128 divides 512 -> single b per tile
    int l0 = row0 & 511;
    float acc[8][8] = {};
    int r = tid >> 1, half = tid & 1;
    int kb = half * 8;
    size_t aoff = ((size_t)gb * L_ + (l0 + r)) * 1024;  // h and x each have 1024 features
    size_t boff = (size_t)(n0 + r) * D_;

    for (int k0 = 0; k0 < D_; k0 += BK) {
        int k = k0 + kb;                     // 1024 % 16 == 0: 8-float run never crosses h/x boundary
        const float* ap = (k < 1024) ? (hs + aoff + k) : (xx + aoff + (k - 1024));
        float4 av0 = *(const float4*)(ap);
        float4 av1 = *(const float4*)(ap + 4);
        float4 bv0 = *(const float4*)(Wa + boff + k);
        float4 bv1 = *(const float4*)(Wa + boff + k + 4);
        __syncthreads();
        As[kb+0][r]=av0.x; As[kb+1][r]=av0.y; As[kb+2][r]=av0.z; As[kb+3][r]=av0.w;
        As[kb+4][r]=av1.x; As[kb+5][r]=av1.y; As[kb+6][r]=av1.z; As[kb+7][r]=av1.w;
        Bs[kb+0][r]=bv0.x; Bs[kb+1][r]=bv0.y; Bs[kb+2][r]=bv0.z; Bs[kb+3][r]=bv0.w;
        Bs[kb+4][r]=bv1.x; Bs[kb+5][r]=bv1.y; Bs[kb+6][r]=bv1.z; Bs[kb+7][r]=bv1.w;
        __syncthreads();
#pragma unroll
        for (int kk = 0; kk < BK; ++kk) {
            float a_[8], b_[8];
            *(float4*)&a_[0] = *(const float4*)&As[kk][ty * 8];
            *(float4*)&a_[4] = *(const float4*)&As[kk][ty * 8 + 4];
            *(float4*)&b_[0] = *(const float4*)&Bs[kk][tx * 8];
            *(float4*)&b_[4] = *(const float4*)&Bs[kk][tx * 8 + 4];
#pragma unroll
            for (int i = 0; i < 8; ++i)
#pragma unroll
                for (int j = 0; j < 8; ++j) acc[i][j] += a_[i] * b_[j];
        }
    }

    float t2v[8];
#pragma unroll
    for (int j = 0; j < 8; ++j) t2v[j] = t2[(size_t)gb * D_ + n0 + tx * 8 + j];

    if (pass == 1) {
        float rp[8];
#pragma unroll
        for (int i = 0; i < 8; ++i) {
            float sum = 0.f;
#pragma unroll
            for (int j = 0; j < 8; ++j) sum += expf(tanhf(acc[i][j] + t2v[j]));
            rp[i] = sum;
        }
        __syncthreads();
        if (tid < BM) red[tid] = 0.f;
        __syncthreads();
#pragma unroll
        for (int i = 0; i < 8; ++i) atomicAdd(&red[ty * 8 + i], rp[i]);
        __syncthreads();
        if (tid < BM) atomicAdd(&rowsum[row0 + tid], red[tid]);
    } else {
        float cs[8] = {};
#pragma unroll
        for (int i = 0; i < 8; ++i) {
            int rr = ty * 8 + i;
            int m = mask[gb * L_ + l0 + rr];
            float inv = (m != 0) ? 1.0f / rowsum[row0 + rr] : 0.0f;
#pragma unroll
            for (int j = 0; j < 8; ++j) cs[j] += expf(tanhf(acc[i][j] + t2v[j])) * inv;
        }
        __syncthreads();
        if (tid < BN) red[tid] = 0.f;
        __syncthreads();
#pragma unroll
        for (int j = 0; j < 8; ++j) atomicAdd(&red[tx * 8 + j], cs[j]);
        __syncthreads();
        if (tid < BN) atomicAdd(&out[(size_t)gb * D_ + n0 + tid], red[tid]);
    }
}

// ---------------- final: out = (attn_sum + cnt0/2048) * trig_a ----------------
__global__ __launch_bounds__(256) void k_final(
    const float* __restrict__ hs, const float* __restrict__ xx,
    const int* __restrict__ trigger, const float* __restrict__ cnt0,
    float* __restrict__ out) {
    int t = blockIdx.x * 256 + threadIdx.x;  // 131072
    int b = t >> 11, e = t & 2047;
    int trig = trigger[b];
    size_t base = ((size_t)b * L_ + trig) * 1024;
    float ta = (e < 1024) ? hs[base + e] : xx[base + e - 1024];
    out[t] = (out[t] + cnt0[b] * (1.0f / 2048.0f)) * ta;
}

extern "C" void kernel_launch(void* const* d_in, const int* in_sizes, int n_in,
                              void* d_out, int out_size, void* d_ws, size_t ws_size,
                              hipStream_t stream) {
    const float* hs = (const float*)d_in[0];
    const float* xx = (const float*)d_in[1];
    const float* Wa = (const float*)d_in[2];
    const float* ba = (const float*)d_in[3];
    const float* Ws = (const float*)d_in[4];
    const float* bs = (const float*)d_in[5];
    const int*   trig = (const int*)d_in[6];
    const int*   mask = (const int*)d_in[7];
    float* out = (float*)d_out;

    float* ws     = (float*)d_ws;
    float* s      = ws;               // 65536 floats
    float* t2     = s + 65536;        // 131072 floats
    float* cnt0   = t2 + 131072;      // 64 floats
    float* rowsum = cnt0 + 64;        // 32768 floats   (total ~0.92 MB)

    hipMemsetAsync(out, 0, (size_t)B_ * D_ * sizeof(float), stream);
    hipMemsetAsync(rowsum, 0, (size_t)B_ * L_ * sizeof(float), stream);

    k_s  <<<256, 256, 0, stream>>>(hs, s);
    k_cnt<<<B_, 256, 0, stream>>>(mask, cnt0);
    k_t2 <<<D_ / 64, 256, 0, stream>>>(s, Ws, ba, bs, t2);

    dim3 grid(D_ / BN, (B_ * L_) / BM);   // 16 x 256
    k_pass<<<grid, 256, 0, stream>>>(hs, xx, Wa, t2, mask, rowsum, out, 1);
    k_pass<<<grid, 256, 0, stream>>>(hs, xx, Wa, t2, mask, rowsum, out, 2);

    k_final<<<(B_ * D_) / 256, 256, 0, stream>>>(hs, xx, trig, cnt0, out);
}

// Round 3
// 1111.903 us; speedup vs baseline: 6.2939x; 6.2939x over previous
//
#include <hip/hip_runtime.h>
#include <cstdint>

#define B_ 64
#define L_ 512
#define H_ 1024
#define D_ 2048

typedef __attribute__((ext_vector_type(8))) short short8;
typedef __attribute__((ext_vector_type(4))) float f32x4;

static __device__ __forceinline__ float bf2f(unsigned int lo16) {
    unsigned int u = lo16 << 16;
    return __builtin_bit_cast(float, u);
}
// round-to-nearest-even fp32 -> bf16 (raw u16)
static __device__ __forceinline__ unsigned short f2bf(float f) {
    unsigned int u = __builtin_bit_cast(unsigned int, f);
    u += 0x7fffu + ((u >> 16) & 1u);
    return (unsigned short)(u >> 16);
}
// pack two fp32 -> two bf16 in one uint (x in low 16, y in high 16)
static __device__ __forceinline__ unsigned int pk(float x, float y) {
    return (unsigned int)f2bf(x) | ((unsigned int)f2bf(y) << 16);
}
// exp(tanh(u)), clamped so expf never overflows
static __device__ __forceinline__ float fast_pexp(float u) {
    u = fminf(15.f, fmaxf(-15.f, u));
    float ex = __expf(2.f * u);
    float th = (ex - 1.f) / (ex + 1.f);
    return __expf(th);
}

// ---------------- s[b,h] = sum_l h_state[b,l,h] ----------------
__global__ __launch_bounds__(256) void k_s(const float* __restrict__ h, float* __restrict__ s) {
    int t = blockIdx.x * 256 + threadIdx.x;
    int b = t >> 10, hh = t & 1023;
    const float* p = h + ((size_t)b * L_) * H_ + hh;
    float acc = 0.f;
#pragma unroll 8
    for (int l = 0; l < L_; ++l) acc += p[(size_t)l * H_];
    s[t] = acc;
}

// ---------------- cnt0[b] = #(mask[b,l]==0) ----------------
__global__ __launch_bounds__(256) void k_cnt(const int* __restrict__ mask, float* __restrict__ cnt0) {
    int b = blockIdx.x, t = threadIdx.x;
    int c = 0;
    for (int l = t; l < L_; l += 256) c += (mask[b * L_ + l] == 0);
    __shared__ int sh[256];
    sh[t] = c; __syncthreads();
    for (int s2 = 128; s2 > 0; s2 >>= 1) { if (t < s2) sh[t] += sh[t + s2]; __syncthreads(); }
    if (t == 0) cnt0[b] = (float)sh[0];
}

// ---------------- t2[b,e] = s[b,:]@W_s[e,:] + b_a[e] + b_s[e] ----------------
__global__ __launch_bounds__(256) void k_t2(const float* __restrict__ s, const float* __restrict__ Ws,
                                            const float* __restrict__ ba, const float* __restrict__ bs,
                                            float* __restrict__ t2) {
    __shared__ float As[16][64];
    __shared__ float Bs[16][64];
    int n0 = blockIdx.x * 64;
    int tid = threadIdx.x;
    int tx = tid & 15, ty = tid >> 4;
    int r = tid >> 2, q = tid & 3;
    float acc[4][4] = {};
    for (int k0 = 0; k0 < H_; k0 += 16) {
        float4 av = *(const float4*)(s + (size_t)r * H_ + k0 + q * 4);
        float4 bv = *(const float4*)(Ws + (size_t)(n0 + r) * H_ + k0 + q * 4);
        __syncthreads();
        As[q*4+0][r] = av.x; As[q*4+1][r] = av.y; As[q*4+2][r] = av.z; As[q*4+3][r] = av.w;
        Bs[q*4+0][r] = bv.x; Bs[q*4+1][r] = bv.y; Bs[q*4+2][r] = bv.z; Bs[q*4+3][r] = bv.w;
        __syncthreads();
#pragma unroll
        for (int kk = 0; kk < 16; ++kk) {
            float a_[4], b_[4];
            *(float4*)&a_[0] = *(const float4*)&As[kk][ty * 4];
            *(float4*)&b_[0] = *(const float4*)&Bs[kk][tx * 4];
#pragma unroll
            for (int i = 0; i < 4; ++i)
#pragma unroll
                for (int j = 0; j < 4; ++j) acc[i][j] += a_[i] * b_[j];
        }
    }
#pragma unroll
    for (int i = 0; i < 4; ++i)
#pragma unroll
        for (int j = 0; j < 4; ++j) {
            int bb = ty * 4 + i, e = n0 + tx * 4 + j;
            t2[(size_t)bb * D_ + e] = acc[i][j] + ba[e] + bs[e];
        }
}

// ---------------- MFMA GEMM: C[row,e] = a[row,:] @ Wa[e,:], fused epilogue ----------------
// mode 0: write P (bf16 exp values) + rowsum        [materialize path]
// mode 1: rowsum only                                [fallback pass 1]
// mode 2: recompute + normalized column accumulation [fallback pass 2]
#define BM 128
#define BN 128
#define BK 32
#define LDK 40   // BK + 8 pad (ushorts) -> row stride 80 B, breaks pow2 bank stride

__global__ __launch_bounds__(256) void k_gemm(
    const float* __restrict__ hs, const float* __restrict__ xx,
    const float* __restrict__ Wa, const float* __restrict__ t2,
    const int* __restrict__ mask, float* __restrict__ rowsum,
    unsigned short* __restrict__ P, float* __restrict__ out, int mode)
{
    __shared__ unsigned short Asl[BM][LDK];
    __shared__ unsigned short Bsl[BN][LDK];
    __shared__ float red[BM];

    int tid = threadIdx.x;
    int lane = tid & 63;
    int w = tid >> 6;
    int wm = w & 1, wn = w >> 1;

    int n0 = blockIdx.x * BN;
    int row0 = blockIdx.y * BM;
    int gb = row0 >> 9;       // BM=128 divides 512: one batch per tile
    int lbase = row0 & 511;

    int r = tid >> 1;
    int koff = (tid & 1) * 16;

    size_t abase = ((size_t)gb * L_ + (lbase + r)) * (size_t)H_;
    const float* hrow = hs + abase;
    const float* xrow = xx + abase;
    const float* brow = Wa + (size_t)(n0 + r) * D_;

    f32x4 acc[4][4] = {};

    for (int k0 = 0; k0 < D_; k0 += BK) {
        int k = k0 + koff;                       // 16-float run never crosses h/x boundary
        const float* ap = (k < H_) ? (hrow + k) : (xrow + (k - H_));
        const float* bp = brow + k;
        float4 a0 = *(const float4*)(ap);
        float4 a1 = *(const float4*)(ap + 4);
        float4 a2 = *(const float4*)(ap + 8);
        float4 a3 = *(const float4*)(ap + 12);
        float4 b0 = *(const float4*)(bp);
        float4 b1 = *(const float4*)(bp + 4);
        float4 b2 = *(const float4*)(bp + 8);
        float4 b3 = *(const float4*)(bp + 12);
        __syncthreads();
        *(uint4*)&Asl[r][koff]     = make_uint4(pk(a0.x,a0.y), pk(a0.z,a0.w), pk(a1.x,a1.y), pk(a1.z,a1.w));
        *(uint4*)&Asl[r][koff + 8] = make_uint4(pk(a2.x,a2.y), pk(a2.z,a2.w), pk(a3.x,a3.y), pk(a3.z,a3.w));
        *(uint4*)&Bsl[r][koff]     = make_uint4(pk(b0.x,b0.y), pk(b0.z,b0.w), pk(b1.x,b1.y), pk(b1.z,b1.w));
        *(uint4*)&Bsl[r][koff + 8] = make_uint4(pk(b2.x,b2.y), pk(b2.z,b2.w), pk(b3.x,b3.y), pk(b3.z,b3.w));
        __syncthreads();
        int kb = (lane >> 4) * 8;
        short8 af[4], bfg[4];
#pragma unroll
        for (int i = 0; i < 4; ++i) af[i]  = *(const short8*)&Asl[wm*64 + i*16 + (lane & 15)][kb];
#pragma unroll
        for (int j = 0; j < 4; ++j) bfg[j] = *(const short8*)&Bsl[wn*64 + j*16 + (lane & 15)][kb];
#pragma unroll
        for (int i = 0; i < 4; ++i)
#pragma unroll
            for (int j = 0; j < 4; ++j)
                acc[i][j] = __builtin_amdgcn_mfma_f32_16x16x32_bf16(af[i], bfg[j], acc[i][j], 0, 0, 0);
    }

    int cl = lane & 15, qd = lane >> 4;
    float t2v[4]; int ecol[4];
#pragma unroll
    for (int j = 0; j < 4; ++j) { ecol[j] = n0 + wn*64 + j*16 + cl; t2v[j] = t2[gb * D_ + ecol[j]]; }

    if (mode <= 1) {
        float rs[4][4] = {};   // [i][reg]
#pragma unroll
        for (int i = 0; i < 4; ++i) {
            int lrowb = wm*64 + i*16 + qd*4;
#pragma unroll
            for (int j = 0; j < 4; ++j) {
#pragma unroll
                for (int g = 0; g < 4; ++g) {
                    float p = fast_pexp(acc[i][j][g] + t2v[j]);
                    rs[i][g] += p;
                    if (mode == 0)
                        P[(size_t)(row0 + lrowb + g) * D_ + ecol[j]] = f2bf(p);
                }
            }
        }
#pragma unroll
        for (int i = 0; i < 4; ++i)
#pragma unroll
            for (int g = 0; g < 4; ++g) {
                float v = rs[i][g];
                v += __shfl_xor(v, 1); v += __shfl_xor(v, 2);
                v += __shfl_xor(v, 4); v += __shfl_xor(v, 8);
                rs[i][g] = v;
            }
        __syncthreads();
        if (tid < BM) red[tid] = 0.f;
        __syncthreads();
        if (cl == 0) {
#pragma unroll
            for (int i = 0; i < 4; ++i)
#pragma unroll
                for (int g = 0; g < 4; ++g)
                    atomicAdd(&red[wm*64 + i*16 + qd*4 + g], rs[i][g]);
        }
        __syncthreads();
        if (tid < BM) atomicAdd(&rowsum[row0 + tid], red[tid]);
    } else {
        float inv[4][4];
#pragma unroll
        for (int i = 0; i < 4; ++i)
#pragma unroll
            for (int g = 0; g < 4; ++g) {
                int lrow = wm*64 + i*16 + qd*4 + g;
                inv[i][g] = mask[gb * L_ + lbase + lrow] ? (1.f / rowsum[row0 + lrow]) : 0.f;
            }
        float cs[4] = {};
#pragma unroll
        for (int i = 0; i < 4; ++i)
#pragma unroll
            for (int j = 0; j < 4; ++j)
#pragma unroll
                for (int g = 0; g < 4; ++g)
                    cs[j] += fast_pexp(acc[i][j][g] + t2v[j]) * inv[i][g];
#pragma unroll
        for (int j = 0; j < 4; ++j) {
            float v = cs[j];
            v += __shfl_xor(v, 16); v += __shfl_xor(v, 32);
            cs[j] = v;
        }
        __syncthreads();
        if (tid < BN) red[tid] = 0.f;
        __syncthreads();
        if (qd == 0) {
#pragma unroll
            for (int j = 0; j < 4; ++j) atomicAdd(&red[wn*64 + j*16 + cl], cs[j]);
        }
        __syncthreads();
        if (tid < BN) atomicAdd(&out[gb * D_ + n0 + tid], red[tid]);
    }
}

// ---------------- invr[row] = mask ? 1/rowsum : 0 ----------------
__global__ __launch_bounds__(256) void k_inv(const int* __restrict__ mask,
                                             const float* __restrict__ rowsum,
                                             float* __restrict__ invr) {
    int t = blockIdx.x * 256 + threadIdx.x;
    invr[t] = mask[t] ? (1.f / rowsum[t]) : 0.f;
}

// ---------------- out[b,e] = sum_l invr[b,l] * P[b*512+l, e] ----------------
__global__ __launch_bounds__(256) void k_fin(const unsigned short* __restrict__ P,
                                             const float* __restrict__ invr,
                                             float* __restrict__ out) {
    int b = blockIdx.y;
    int e0 = blockIdx.x * 512 + threadIdx.x * 2;
    int lz = blockIdx.z * 128;
    const unsigned short* Pb = P + ((size_t)b * L_ + lz) * D_ + e0;
    const float* ivb = invr + b * L_ + lz;
    float s0 = 0.f, s1 = 0.f;
    for (int l = 0; l < 128; ++l) {
        float iv = ivb[l];
        unsigned int pv = *(const unsigned int*)(Pb + (size_t)l * D_);
        s0 += iv * bf2f(pv & 0xffffu);
        s1 += iv * bf2f(pv >> 16);
    }
    atomicAdd(&out[b * D_ + e0], s0);
    atomicAdd(&out[b * D_ + e0 + 1], s1);
}

// ---------------- final: out = (attn_sum + cnt0/2048) * trig_a ----------------
__global__ __launch_bounds__(256) void k_final(
    const float* __restrict__ hs, const float* __restrict__ xx,
    const int* __restrict__ trigger, const float* __restrict__ cnt0,
    float* __restrict__ out) {
    int t = blockIdx.x * 256 + threadIdx.x;
    int b = t >> 11, e = t & 2047;
    int trig = trigger[b];
    size_t base = ((size_t)b * L_ + trig) * 1024;
    float ta = (e < 1024) ? hs[base + e] : xx[base + e - 1024];
    out[t] = (out[t] + cnt0[b] * (1.0f / 2048.0f)) * ta;
}

extern "C" void kernel_launch(void* const* d_in, const int* in_sizes, int n_in,
                              void* d_out, int out_size, void* d_ws, size_t ws_size,
                              hipStream_t stream) {
    const float* hs = (const float*)d_in[0];
    const float* xx = (const float*)d_in[1];
    const float* Wa = (const float*)d_in[2];
    const float* ba = (const float*)d_in[3];
    const float* Ws = (const float*)d_in[4];
    const float* bs = (const float*)d_in[5];
    const int*   trig = (const int*)d_in[6];
    const int*   mask = (const int*)d_in[7];
    float* out = (float*)d_out;

    float* ws     = (float*)d_ws;
    float* s      = ws;                 // 65536
    float* t2     = s + 65536;          // 131072
    float* cnt0   = t2 + 131072;        // 64
    float* rowsum = cnt0 + 64;          // 32768
    float* invr   = rowsum + 32768;     // 32768
    unsigned short* P = (unsigned short*)(invr + 32768);   // byte off 1048832, 16B aligned

    size_t NEED = 1048832ull + (size_t)B_ * L_ * D_ * 2ull;  // ~135.3 MB
    bool fullws = ws_size >= NEED;

    (void)hipMemsetAsync(out, 0, (size_t)B_ * D_ * sizeof(float), stream);
    (void)hipMemsetAsync(rowsum, 0, (size_t)B_ * L_ * sizeof(float), stream);

    k_s  <<<256, 256, 0, stream>>>(hs, s);
    k_cnt<<<B_, 256, 0, stream>>>(mask, cnt0);
    k_t2 <<<D_ / 64, 256, 0, stream>>>(s, Ws, ba, bs, t2);

    dim3 grid(D_ / BN, (B_ * L_) / BM);   // 16 x 256
    if (fullws) {
        k_gemm<<<grid, 256, 0, stream>>>(hs, xx, Wa, t2, mask, rowsum, P, out, 0);
        k_inv<<<(B_ * L_) / 256, 256, 0, stream>>>(mask, rowsum, invr);
        k_fin<<<dim3(4, 64, 4), 256, 0, stream>>>(P, invr, out);
    } else {
        k_gemm<<<grid, 256, 0, stream>>>(hs, xx, Wa, t2, mask, rowsum, P, out, 1);
        k_gemm<<<grid, 256, 0, stream>>>(hs, xx, Wa, t2, mask, rowsum, P, out, 2);
    }
    k_final<<<(B_ * D_) / 256, 256, 0, stream>>>(hs, xx, trig, cnt0, out);
}

// Round 4
// 905.170 us; speedup vs baseline: 7.7314x; 1.2284x over previous
//
#include <hip/hip_runtime.h>
#include <cstdint>

#define B_ 64
#define L_ 512
#define H_ 1024
#define D_ 2048

typedef __attribute__((ext_vector_type(8))) short short8;
typedef __attribute__((ext_vector_type(4))) float f32x4;

static __device__ __forceinline__ float bf2f(unsigned int lo16) {
    unsigned int u = lo16 << 16;
    return __builtin_bit_cast(float, u);
}
// round-to-nearest-even fp32 -> bf16 (raw u16)
static __device__ __forceinline__ unsigned short f2bf(float f) {
    unsigned int u = __builtin_bit_cast(unsigned int, f);
    u += 0x7fffu + ((u >> 16) & 1u);
    return (unsigned short)(u >> 16);
}
static __device__ __forceinline__ unsigned int pk(float x, float y) {
    return (unsigned int)f2bf(x) | ((unsigned int)f2bf(y) << 16);
}
// exp(tanh(u)), clamped so expf never overflows
static __device__ __forceinline__ float fast_pexp(float u) {
    u = fminf(15.f, fmaxf(-15.f, u));
    float ex = __expf(2.f * u);
    float th = (ex - 1.f) / (ex + 1.f);
    return __expf(th);
}

// ---------------- s[b,h] = sum_l h_state[b,l,h] ----------------
__global__ __launch_bounds__(256) void k_s(const float* __restrict__ h, float* __restrict__ s) {
    int t = blockIdx.x * 256 + threadIdx.x;
    int b = t >> 10, hh = t & 1023;
    const float* p = h + ((size_t)b * L_) * H_ + hh;
    float acc = 0.f;
#pragma unroll 8
    for (int l = 0; l < L_; ++l) acc += p[(size_t)l * H_];
    s[t] = acc;
}

// ---------------- compaction: ridx[b][j]=j-th masked-in l; cnt1[b]; cnt0[b] ----------------
__global__ __launch_bounds__(256) void k_compact(const int* __restrict__ mask,
                                                 int* __restrict__ ridx,
                                                 int* __restrict__ cnt1,
                                                 float* __restrict__ cnt0) {
    int b = blockIdx.x;
    __shared__ int sm[L_];
    for (int l = threadIdx.x; l < L_; l += 256) sm[l] = mask[b * L_ + l];
    __syncthreads();
    if (threadIdx.x == 0) {
        int* rb = ridx + b * L_;
        int c = 0;
        for (int l = 0; l < L_; ++l) if (sm[l]) rb[c++] = l;
        int n1 = c;
        int last = (c > 0) ? rb[c - 1] : 0;
        for (; c < L_; ++c) rb[c] = last;   // pad with last valid (finite loads)
        cnt1[b] = n1;
        cnt0[b] = (float)(L_ - n1);
    }
}

// ---------------- Wb = bf16(W_a) ----------------
__global__ __launch_bounds__(256) void k_cvtW(const float* __restrict__ Wa,
                                              unsigned short* __restrict__ Wb) {
    int t = blockIdx.x * 256 + threadIdx.x;      // 1,048,576 threads
    float4 v = ((const float4*)Wa)[t];
    ((uint2*)Wb)[t] = make_uint2(pk(v.x, v.y), pk(v.z, v.w));
}

// ---------------- t2 init: ba + bs ----------------
__global__ __launch_bounds__(256) void k_t2init(const float* __restrict__ ba,
                                                const float* __restrict__ bs,
                                                float* __restrict__ t2) {
    int t = blockIdx.x * 256 + threadIdx.x;      // 131072
    int e = t & 2047;
    t2[t] = ba[e] + bs[e];
}

// ---------------- t2 += s @ W_s^T  (split-K, atomic reduce) ----------------
__global__ __launch_bounds__(256) void k_t2(const float* __restrict__ s, const float* __restrict__ Ws,
                                            float* __restrict__ t2) {
    __shared__ float As[16][64];
    __shared__ float Bs[16][64];
    int n0 = blockIdx.x * 64;
    int ks0 = blockIdx.y * 256;
    int tid = threadIdx.x;
    int tx = tid & 15, ty = tid >> 4;
    int r = tid >> 2, q = tid & 3;
    float acc[4][4] = {};
    for (int k0 = ks0; k0 < ks0 + 256; k0 += 16) {
        float4 av = *(const float4*)(s + (size_t)r * H_ + k0 + q * 4);
        float4 bv = *(const float4*)(Ws + (size_t)(n0 + r) * H_ + k0 + q * 4);
        __syncthreads();
        As[q*4+0][r] = av.x; As[q*4+1][r] = av.y; As[q*4+2][r] = av.z; As[q*4+3][r] = av.w;
        Bs[q*4+0][r] = bv.x; Bs[q*4+1][r] = bv.y; Bs[q*4+2][r] = bv.z; Bs[q*4+3][r] = bv.w;
        __syncthreads();
#pragma unroll
        for (int kk = 0; kk < 16; ++kk) {
            float a_[4], b_[4];
            *(float4*)&a_[0] = *(const float4*)&As[kk][ty * 4];
            *(float4*)&b_[0] = *(const float4*)&Bs[kk][tx * 4];
#pragma unroll
            for (int i = 0; i < 4; ++i)
#pragma unroll
                for (int j = 0; j < 4; ++j) acc[i][j] += a_[i] * b_[j];
        }
    }
#pragma unroll
    for (int i = 0; i < 4; ++i)
#pragma unroll
        for (int j = 0; j < 4; ++j)
            atomicAdd(&t2[(size_t)(ty * 4 + i) * D_ + n0 + tx * 4 + j], acc[i][j]);
}

// ---------------- MFMA GEMM over compacted rows ----------------
// mode 0: write P (bf16 exp values) + rowsum        [materialize path]
// mode 1: rowsum only                                [fallback pass 1]
// mode 2: recompute + normalized column accumulation [fallback pass 2]
#define BM 128
#define BN 128
#define BK 32
#define LDK 40   // A-tile pad: BK + 8 ushorts

__global__ __launch_bounds__(256) void k_gemm(
    const float* __restrict__ hs, const float* __restrict__ xx,
    const float* __restrict__ Wa, const unsigned short* __restrict__ Wb,
    const float* __restrict__ t2,
    const int* __restrict__ ridx, const int* __restrict__ cnt1,
    float* __restrict__ rowsum,
    unsigned short* __restrict__ P, float* __restrict__ out, int mode)
{
    __shared__ unsigned short Asl[BM][LDK];
    __shared__ unsigned short Bsl[BN][BK];    // unpadded (m97-style layout)
    __shared__ float red[BM];

    int tid = threadIdx.x;
    int lane = tid & 63;
    int w = tid >> 6;
    int wm = w & 1, wn = w >> 1;

    int n0 = blockIdx.x * BN;
    int jt = blockIdx.y;
    int b = jt >> 2;
    int j0 = (jt & 3) * BM;
    int n1 = cnt1[b];
    if (j0 >= n1) return;                      // tile entirely past compacted rows

    int r = tid >> 1;
    int koff = (tid & 1) * 16;
    int l = ridx[b * L_ + j0 + r];
    size_t abase = ((size_t)b * L_ + l) * (size_t)H_;
    const float* hrow = hs + abase;
    const float* xrow = xx + abase;
    const float* browf = Wa + (size_t)(n0 + r) * D_;
    // bf16-B path: chunk cc = q*256 + tid ; row = cc>>2 ; 8-elem group = cc&3
    const unsigned short* bw0 = Wb + (size_t)(n0 + (tid >> 2)) * D_ + (tid & 3) * 8;
    const unsigned short* bw1 = Wb + (size_t)(n0 + 64 + (tid >> 2)) * D_ + (tid & 3) * 8;
    unsigned short* bs0 = &Bsl[0][0] + (size_t)tid * 8;
    unsigned short* bs1 = &Bsl[0][0] + (size_t)(tid + 256) * 8;
    bool useWb = (Wb != nullptr);

    f32x4 acc[4][4] = {};

    for (int k0 = 0; k0 < D_; k0 += BK) {
        int k = k0 + koff;                     // 16-float run never crosses h/x boundary
        const float* ap = (k < H_) ? (hrow + k) : (xrow + (k - H_));
        float4 a0 = *(const float4*)(ap);
        float4 a1 = *(const float4*)(ap + 4);
        float4 a2 = *(const float4*)(ap + 8);
        float4 a3 = *(const float4*)(ap + 12);
        uint4 bv0, bv1;
        float4 c0, c1, c2, c3;
        if (useWb) {
            bv0 = *(const uint4*)(bw0 + k0);
            bv1 = *(const uint4*)(bw1 + k0);
        } else {
            const float* bp = browf + k;
            c0 = *(const float4*)(bp);
            c1 = *(const float4*)(bp + 4);
            c2 = *(const float4*)(bp + 8);
            c3 = *(const float4*)(bp + 12);
        }
        __syncthreads();
        *(uint4*)&Asl[r][koff]     = make_uint4(pk(a0.x,a0.y), pk(a0.z,a0.w), pk(a1.x,a1.y), pk(a1.z,a1.w));
        *(uint4*)&Asl[r][koff + 8] = make_uint4(pk(a2.x,a2.y), pk(a2.z,a2.w), pk(a3.x,a3.y), pk(a3.z,a3.w));
        if (useWb) {
            *(uint4*)bs0 = bv0;
            *(uint4*)bs1 = bv1;
        } else {
            *(uint4*)&Bsl[r][koff]     = make_uint4(pk(c0.x,c0.y), pk(c0.z,c0.w), pk(c1.x,c1.y), pk(c1.z,c1.w));
            *(uint4*)&Bsl[r][koff + 8] = make_uint4(pk(c2.x,c2.y), pk(c2.z,c2.w), pk(c3.x,c3.y), pk(c3.z,c3.w));
        }
        __syncthreads();
        int kb = (lane >> 4) * 8;
        short8 af[4], bfg[4];
#pragma unroll
        for (int i = 0; i < 4; ++i) af[i]  = *(const short8*)&Asl[wm*64 + i*16 + (lane & 15)][kb];
#pragma unroll
        for (int j = 0; j < 4; ++j) bfg[j] = *(const short8*)&Bsl[wn*64 + j*16 + (lane & 15)][kb];
#pragma unroll
        for (int i = 0; i < 4; ++i)
#pragma unroll
            for (int j = 0; j < 4; ++j)
                acc[i][j] = __builtin_amdgcn_mfma_f32_16x16x32_bf16(af[i], bfg[j], acc[i][j], 0, 0, 0);
    }

    int cl = lane & 15, qd = lane >> 4;
    float t2v[4]; int ecol[4];
#pragma unroll
    for (int j = 0; j < 4; ++j) { ecol[j] = n0 + wn*64 + j*16 + cl; t2v[j] = t2[b * D_ + ecol[j]]; }
    int orow0 = b * L_ + j0;                   // compacted-row base

    if (mode <= 1) {
        float rs[4][4] = {};
#pragma unroll
        for (int i = 0; i < 4; ++i) {
            int lrowb = wm*64 + i*16 + qd*4;
#pragma unroll
            for (int j = 0; j < 4; ++j) {
#pragma unroll
                for (int g = 0; g < 4; ++g) {
                    float p = fast_pexp(acc[i][j][g] + t2v[j]);
                    rs[i][g] += p;
                    if (mode == 0)
                        P[(size_t)(orow0 + lrowb + g) * D_ + ecol[j]] = f2bf(p);
                }
            }
        }
#pragma unroll
        for (int i = 0; i < 4; ++i)
#pragma unroll
            for (int g = 0; g < 4; ++g) {
                float v = rs[i][g];
                v += __shfl_xor(v, 1); v += __shfl_xor(v, 2);
                v += __shfl_xor(v, 4); v += __shfl_xor(v, 8);
                rs[i][g] = v;
            }
        __syncthreads();
        if (tid < BM) red[tid] = 0.f;
        __syncthreads();
        if (cl == 0) {
#pragma unroll
            for (int i = 0; i < 4; ++i)
#pragma unroll
                for (int g = 0; g < 4; ++g)
                    atomicAdd(&red[wm*64 + i*16 + qd*4 + g], rs[i][g]);
        }
        __syncthreads();
        if (tid < BM) atomicAdd(&rowsum[orow0 + tid], red[tid]);
    } else {
        float inv[4][4];
#pragma unroll
        for (int i = 0; i < 4; ++i)
#pragma unroll
            for (int g = 0; g < 4; ++g) {
                int lrow = wm*64 + i*16 + qd*4 + g;
                inv[i][g] = (j0 + lrow < n1) ? (1.f / rowsum[orow0 + lrow]) : 0.f;
            }
        float cs[4] = {};
#pragma unroll
        for (int i = 0; i < 4; ++i)
#pragma unroll
            for (int j = 0; j < 4; ++j)
#pragma unroll
                for (int g = 0; g < 4; ++g)
                    cs[j] += fast_pexp(acc[i][j][g] + t2v[j]) * inv[i][g];
#pragma unroll
        for (int j = 0; j < 4; ++j) {
            float v = cs[j];
            v += __shfl_xor(v, 16); v += __shfl_xor(v, 32);
            cs[j] = v;
        }
        __syncthreads();
        if (tid < BN) red[tid] = 0.f;
        __syncthreads();
        if (qd == 0) {
#pragma unroll
            for (int j = 0; j < 4; ++j) atomicAdd(&red[wn*64 + j*16 + cl], cs[j]);
        }
        __syncthreads();
        if (tid < BN) atomicAdd(&out[b * D_ + n0 + tid], red[tid]);
    }
}

// ---------------- invr[b,j] = (j<cnt1[b]) ? 1/rowsum : 0 ----------------
__global__ __launch_bounds__(256) void k_inv(const int* __restrict__ cnt1,
                                             const float* __restrict__ rowsum,
                                             float* __restrict__ invr) {
    int t = blockIdx.x * 256 + threadIdx.x;
    int b = t >> 9, j = t & 511;
    invr[t] = (j < cnt1[b]) ? (1.f / rowsum[t]) : 0.f;
}

// ---------------- out[b,e] = sum_j invr[b,j] * P[b*512+j, e] ----------------
__global__ __launch_bounds__(256) void k_fin(const unsigned short* __restrict__ P,
                                             const float* __restrict__ invr,
                                             const int* __restrict__ cnt1,
                                             float* __restrict__ out) {
    int b = blockIdx.y;
    int lz = blockIdx.z * 128;
    if (lz >= cnt1[b]) return;                 // fully-invalid tile: skip (P is poison there)
    int e0 = blockIdx.x * 512 + threadIdx.x * 2;
    const unsigned short* Pb = P + ((size_t)b * L_ + lz) * D_ + e0;
    const float* ivb = invr + b * L_ + lz;
    float s0 = 0.f, s1 = 0.f;
    for (int l = 0; l < 128; ++l) {
        float iv = ivb[l];
        unsigned int pv = *(const unsigned int*)(Pb + (size_t)l * D_);
        s0 += iv * bf2f(pv & 0xffffu);
        s1 += iv * bf2f(pv >> 16);
    }
    atomicAdd(&out[b * D_ + e0], s0);
    atomicAdd(&out[b * D_ + e0 + 1], s1);
}

// ---------------- final: out = (attn_sum + cnt0/2048) * trig_a ----------------
__global__ __launch_bounds__(256) void k_final(
    const float* __restrict__ hs, const float* __restrict__ xx,
    const int* __restrict__ trigger, const float* __restrict__ cnt0,
    float* __restrict__ out) {
    int t = blockIdx.x * 256 + threadIdx.x;
    int b = t >> 11, e = t & 2047;
    int trig = trigger[b];
    size_t base = ((size_t)b * L_ + trig) * 1024;
    float ta = (e < 1024) ? hs[base + e] : xx[base + e - 1024];
    out[t] = (out[t] + cnt0[b] * (1.0f / 2048.0f)) * ta;
}

extern "C" void kernel_launch(void* const* d_in, const int* in_sizes, int n_in,
                              void* d_out, int out_size, void* d_ws, size_t ws_size,
                              hipStream_t stream) {
    const float* hs = (const float*)d_in[0];
    const float* xx = (const float*)d_in[1];
    const float* Wa = (const float*)d_in[2];
    const float* ba = (const float*)d_in[3];
    const float* Ws = (const float*)d_in[4];
    const float* bs = (const float*)d_in[5];
    const int*   trig = (const int*)d_in[6];
    const int*   mask = (const int*)d_in[7];
    float* out = (float*)d_out;

    float* wsf    = (float*)d_ws;
    float* s      = wsf;                 // 65536
    float* t2     = s + 65536;           // 131072
    float* cnt0   = t2 + 131072;         // 64
    float* rowsum = cnt0 + 64;           // 32768
    float* invr   = rowsum + 32768;      // 32768
    int*   cnt1   = (int*)(invr + 32768);// 64
    int*   ridx   = cnt1 + 64;           // 32768
    unsigned short* P  = (unsigned short*)(ridx + 32768);      // 134,217,728 B
    unsigned short* Wb = P + (size_t)B_ * L_ * D_;             // 8,388,608 B

    const size_t BASE_B  = 295040ull * 4ull;                   // 1,180,160
    const size_t NEED1   = BASE_B + 134217728ull;              // P
    const size_t NEED2   = NEED1 + 8388608ull;                 // + Wb
    bool haveP  = ws_size >= NEED1;
    bool haveWb = ws_size >= NEED2;
    const unsigned short* WbArg = haveWb ? Wb : nullptr;

    (void)hipMemsetAsync(out, 0, (size_t)B_ * D_ * sizeof(float), stream);
    (void)hipMemsetAsync(rowsum, 0, (size_t)B_ * L_ * sizeof(float), stream);

    k_s      <<<256, 256, 0, stream>>>(hs, s);
    k_compact<<<B_, 256, 0, stream>>>(mask, ridx, cnt1, cnt0);
    if (haveWb) k_cvtW<<<4096, 256, 0, stream>>>(Wa, Wb);
    k_t2init <<<512, 256, 0, stream>>>(ba, bs, t2);
    k_t2     <<<dim3(32, 4), 256, 0, stream>>>(s, Ws, t2);

    dim3 grid(D_ / BN, (B_ * L_) / BM);   // 16 x 256 (blocks past cnt1 self-exit)
    if (haveP) {
        k_gemm<<<grid, 256, 0, stream>>>(hs, xx, Wa, WbArg, t2, ridx, cnt1, rowsum, P, out, 0);
        k_inv <<<(B_ * L_) / 256, 256, 0, stream>>>(cnt1, rowsum, invr);
        k_fin <<<dim3(4, 64, 4), 256, 0, stream>>>(P, invr, cnt1, out);
    } else {
        k_gemm<<<grid, 256, 0, stream>>>(hs, xx, Wa, nullptr, t2, ridx, cnt1, rowsum, P, out, 1);
        k_gemm<<<grid, 256, 0, stream>>>(hs, xx, Wa, nullptr, t2, ridx, cnt1, rowsum, P, out, 2);
    }
    k_final<<<(B_ * D_) / 256, 256, 0, stream>>>(hs, xx, trig, cnt0, out);
}

// Round 5
// 678.330 us; speedup vs baseline: 10.3168x; 1.3344x over previous
//
#include <hip/hip_runtime.h>
#include <cstdint>

#define B_ 64
#define L_ 512
#define H_ 1024
#define D_ 2048

typedef __attribute__((ext_vector_type(8))) short short8;
typedef __attribute__((ext_vector_type(4))) float f32x4;
typedef unsigned int u32;

static __device__ __forceinline__ float bf2f(u32 lo16) {
    u32 u = lo16 << 16;
    return __builtin_bit_cast(float, u);
}
static __device__ __forceinline__ unsigned short f2bf(float f) {
    u32 u = __builtin_bit_cast(u32, f);
    u += 0x7fffu + ((u >> 16) & 1u);
    return (unsigned short)(u >> 16);
}
static __device__ __forceinline__ u32 pk(float x, float y) {
    return (u32)f2bf(x) | ((u32)f2bf(y) << 16);
}
static __device__ __forceinline__ float fast_pexp(float u) {
    u = fminf(15.f, fmaxf(-15.f, u));
    float ex = __expf(2.f * u);
    float th = (ex - 1.f) / (ex + 1.f);
    return __expf(th);
}
// async global->LDS, 16B per lane; lds base must be wave-uniform (HW: base + lane*16)
static __device__ __forceinline__ void gload_lds16(const unsigned short* g, unsigned short* l) {
    __builtin_amdgcn_global_load_lds((const __attribute__((address_space(1))) u32*)g,
                                     (__attribute__((address_space(3))) u32*)l, 16, 0, 0);
}

// ---------------- s[b,h] = sum_l h_state[b,l,h] ----------------
__global__ __launch_bounds__(256) void k_s(const float* __restrict__ h, float* __restrict__ s) {
    int t = blockIdx.x * 256 + threadIdx.x;
    int b = t >> 10, hh = t & 1023;
    const float* p = h + ((size_t)b * L_) * H_ + hh;
    float acc = 0.f;
#pragma unroll 8
    for (int l = 0; l < L_; ++l) acc += p[(size_t)l * H_];
    s[t] = acc;
}

// ---------------- compaction + t2 bias init ----------------
__global__ __launch_bounds__(256) void k_compact(const int* __restrict__ mask,
                                                 const float* __restrict__ ba,
                                                 const float* __restrict__ bs,
                                                 int* __restrict__ ridx,
                                                 int* __restrict__ cnt1,
                                                 float* __restrict__ cnt0,
                                                 float* __restrict__ t2) {
    int b = blockIdx.x;
    __shared__ int sm[L_];
    for (int l = threadIdx.x; l < L_; l += 256) sm[l] = mask[b * L_ + l];
    for (int e = threadIdx.x; e < D_; e += 256) t2[b * D_ + e] = ba[e] + bs[e];
    __syncthreads();
    if (threadIdx.x == 0) {
        int* rb = ridx + b * L_;
        int c = 0;
        for (int l = 0; l < L_; ++l) if (sm[l]) rb[c++] = l;
        int n1 = c;
        int last = (c > 0) ? rb[c - 1] : 0;
        for (; c < L_; ++c) rb[c] = last;
        cnt1[b] = n1;
        cnt0[b] = (float)(L_ - n1);
    }
}

// ---------------- Wb = bf16(W_a) ----------------
__global__ __launch_bounds__(256) void k_cvtW(const float* __restrict__ Wa,
                                              unsigned short* __restrict__ Wb) {
    int t = blockIdx.x * 256 + threadIdx.x;
    float4 v = ((const float4*)Wa)[t];
    ((uint2*)Wb)[t] = make_uint2(pk(v.x, v.y), pk(v.z, v.w));
}

// ---------------- Abf[b,j,:] = bf16([hs | xx][b, ridx[b,j], :])  (compacted gather) ----------------
__global__ __launch_bounds__(256) void k_prep(const float* __restrict__ hs, const float* __restrict__ xx,
                                              const int* __restrict__ ridx, const int* __restrict__ cnt1,
                                              unsigned short* __restrict__ Abf) {
    int j = blockIdx.x;
    int b = blockIdx.y;
    int n1 = cnt1[b];
    if (j >= ((n1 + 127) & ~127)) return;      // rows beyond last active tile never read
    int l = ridx[b * L_ + j];
    int t = threadIdx.x;
    size_t rb = ((size_t)(b * L_ + l)) << 10;
    const float* src = (t < 128) ? (hs + rb + t * 8) : (xx + rb + (t - 128) * 8);
    float4 v0 = *(const float4*)src;
    float4 v1 = *(const float4*)(src + 4);
    *(uint4*)(Abf + (((size_t)(b * L_ + j)) << 11) + t * 8) =
        make_uint4(pk(v0.x, v0.y), pk(v0.z, v0.w), pk(v1.x, v1.y), pk(v1.z, v1.w));
}

// ---------------- t2 += s @ W_s^T  (split-K, atomic reduce) ----------------
__global__ __launch_bounds__(256) void k_t2(const float* __restrict__ s, const float* __restrict__ Ws,
                                            float* __restrict__ t2) {
    __shared__ float As[16][64];
    __shared__ float Bs[16][64];
    int n0 = blockIdx.x * 64;
    int ks0 = blockIdx.y * 256;
    int tid = threadIdx.x;
    int tx = tid & 15, ty = tid >> 4;
    int r = tid >> 2, q = tid & 3;
    float acc[4][4] = {};
    for (int k0 = ks0; k0 < ks0 + 256; k0 += 16) {
        float4 av = *(const float4*)(s + (size_t)r * H_ + k0 + q * 4);
        float4 bv = *(const float4*)(Ws + (size_t)(n0 + r) * H_ + k0 + q * 4);
        __syncthreads();
        As[q*4+0][r] = av.x; As[q*4+1][r] = av.y; As[q*4+2][r] = av.z; As[q*4+3][r] = av.w;
        Bs[q*4+0][r] = bv.x; Bs[q*4+1][r] = bv.y; Bs[q*4+2][r] = bv.z; Bs[q*4+3][r] = bv.w;
        __syncthreads();
#pragma unroll
        for (int kk = 0; kk < 16; ++kk) {
            float a_[4], b_[4];
            *(float4*)&a_[0] = *(const float4*)&As[kk][ty * 4];
            *(float4*)&b_[0] = *(const float4*)&Bs[kk][tx * 4];
#pragma unroll
            for (int i = 0; i < 4; ++i)
#pragma unroll
                for (int j = 0; j < 4; ++j) acc[i][j] += a_[i] * b_[j];
        }
    }
#pragma unroll
    for (int i = 0; i < 4; ++i)
#pragma unroll
        for (int j = 0; j < 4; ++j)
            atomicAdd(&t2[(size_t)(ty * 4 + i) * D_ + n0 + tx * 4 + j], acc[i][j]);
}

#define BM 128
#define BN 128
#define BK 32

// ---------------- v2 MFMA GEMM: pure-bf16 inputs, global_load_lds staging ----------------
__global__ __launch_bounds__(256) void k_gemm2(
    const unsigned short* __restrict__ Abf, const unsigned short* __restrict__ Wb,
    const float* __restrict__ t2, const int* __restrict__ cnt1,
    float* __restrict__ rowsum, unsigned short* __restrict__ P)
{
    __shared__ unsigned short Asl[BM * BK];   // [row][32] unpadded (global_load_lds layout)
    __shared__ unsigned short Bsl[BN * BK];
    __shared__ float red[BM];

    int tid = threadIdx.x;
    int lane = tid & 63;
    int w = tid >> 6;
    int wm = w & 1, wn = w >> 1;

    int n0 = blockIdx.x * BN;
    int jt = blockIdx.y;
    int b = jt >> 2;
    int j0 = (jt & 3) * BM;
    int n1 = cnt1[b];
    if (j0 >= n1) return;

    // staging addresses: lane j -> row w*32 + i*16 + (j>>2), 16B chunk (j&3) within 64B row-seg
    const unsigned short* ga = Abf + (((size_t)(b * L_ + j0 + w * 32 + (lane >> 2))) << 11) + (lane & 3) * 8;
    const unsigned short* gb = Wb  + (((size_t)(n0 + w * 32 + (lane >> 2))) << 11) + (lane & 3) * 8;
    unsigned short* la = &Asl[w * 1024];      // wave-uniform LDS base (bytes: w*2048)
    unsigned short* lb = &Bsl[w * 1024];

    int cl = lane & 15, kb = (lane >> 4) * 8;
    f32x4 acc[4][4] = {};

    for (int k0 = 0; k0 < D_; k0 += BK) {
        __syncthreads();                       // prior iter's ds_reads done
        gload_lds16(ga + k0,         la);
        gload_lds16(ga + 32768 + k0, la + 512);   // +16 rows
        gload_lds16(gb + k0,         lb);
        gload_lds16(gb + 32768 + k0, lb + 512);
        __syncthreads();                       // staging complete (vmcnt drained)
        short8 af[4], bfg[4];
#pragma unroll
        for (int i = 0; i < 4; ++i) af[i]  = *(const short8*)&Asl[(wm*64 + i*16 + cl) * BK + kb];
#pragma unroll
        for (int j = 0; j < 4; ++j) bfg[j] = *(const short8*)&Bsl[(wn*64 + j*16 + cl) * BK + kb];
#pragma unroll
        for (int i = 0; i < 4; ++i)
#pragma unroll
            for (int j = 0; j < 4; ++j)
                acc[i][j] = __builtin_amdgcn_mfma_f32_16x16x32_bf16(af[i], bfg[j], acc[i][j], 0, 0, 0);
    }

    int qd = lane >> 4;
    float t2v[4]; int ecol[4];
#pragma unroll
    for (int j = 0; j < 4; ++j) { ecol[j] = n0 + wn*64 + j*16 + cl; t2v[j] = t2[b * D_ + ecol[j]]; }
    int orow0 = b * L_ + j0;

    float rs[4][4] = {};
#pragma unroll
    for (int i = 0; i < 4; ++i) {
        int lrowb = wm*64 + i*16 + qd*4;
#pragma unroll
        for (int j = 0; j < 4; ++j) {
#pragma unroll
            for (int g = 0; g < 4; ++g) {
                float p = fast_pexp(acc[i][j][g] + t2v[j]);
                rs[i][g] += p;
                P[(size_t)(orow0 + lrowb + g) * D_ + ecol[j]] = f2bf(p);
            }
        }
    }
#pragma unroll
    for (int i = 0; i < 4; ++i)
#pragma unroll
        for (int g = 0; g < 4; ++g) {
            float v = rs[i][g];
            v += __shfl_xor(v, 1); v += __shfl_xor(v, 2);
            v += __shfl_xor(v, 4); v += __shfl_xor(v, 8);
            rs[i][g] = v;
        }
    __syncthreads();
    if (tid < BM) red[tid] = 0.f;
    __syncthreads();
    if (cl == 0) {
#pragma unroll
        for (int i = 0; i < 4; ++i)
#pragma unroll
            for (int g = 0; g < 4; ++g)
                atomicAdd(&red[wm*64 + i*16 + qd*4 + g], rs[i][g]);
    }
    __syncthreads();
    if (tid < BM) atomicAdd(&rowsum[orow0 + tid], red[tid]);
}

// ---------------- v2 finale: out[b,e] = (sum_j P/rowsum + cnt0/2048) * trig_a ----------------
__global__ __launch_bounds__(256) void k_fin2(const unsigned short* __restrict__ P,
                                              const float* __restrict__ rowsum,
                                              const int* __restrict__ cnt1,
                                              const int* __restrict__ trigger,
                                              const float* __restrict__ hs,
                                              const float* __restrict__ xx,
                                              float* __restrict__ out) {
    int b = blockIdx.y;
    __shared__ float iv[L_];
    int n1 = cnt1[b];
    int lceil = (n1 + 127) & ~127;
    for (int j = threadIdx.x; j < L_; j += 256)
        iv[j] = (j < n1) ? 1.f / rowsum[b * L_ + j] : 0.f;
    __syncthreads();
    int e0 = blockIdx.x * 512 + threadIdx.x * 2;
    const unsigned short* Pb = P + (((size_t)b) << 20) + e0;
    float s0 = 0.f, s1 = 0.f;
#pragma unroll 8
    for (int l = 0; l < lceil; ++l) {
        float f = iv[l];
        u32 pv = *(const u32*)(Pb + (((size_t)l) << 11));
        s0 += f * bf2f(pv & 0xffffu);
        s1 += f * bf2f(pv >> 16);
    }
    float base = (float)(L_ - n1) * (1.f / 2048.f);
    int trig = trigger[b];
    size_t tb = ((size_t)(b * L_ + trig)) << 10;
    float ta0 = (e0 < 1024) ? hs[tb + e0] : xx[tb + e0 - 1024];
    float ta1 = (e0 + 1 < 1024) ? hs[tb + e0 + 1] : xx[tb + e0 + 1 - 1024];
    out[b * D_ + e0]     = (s0 + base) * ta0;
    out[b * D_ + e0 + 1] = (s1 + base) * ta1;
}

// ================= v1 fallback kernels (round-4, proven) =================
#define LDK 40
__global__ __launch_bounds__(256) void k_gemm(
    const float* __restrict__ hs, const float* __restrict__ xx,
    const float* __restrict__ Wa, const unsigned short* __restrict__ Wb,
    const float* __restrict__ t2,
    const int* __restrict__ ridx, const int* __restrict__ cnt1,
    float* __restrict__ rowsum,
    unsigned short* __restrict__ P, float* __restrict__ out, int mode)
{
    __shared__ unsigned short Asl[BM][LDK];
    __shared__ unsigned short Bsl[BN][BK];
    __shared__ float red[BM];

    int tid = threadIdx.x;
    int lane = tid & 63;
    int w = tid >> 6;
    int wm = w & 1, wn = w >> 1;

    int n0 = blockIdx.x * BN;
    int jt = blockIdx.y;
    int b = jt >> 2;
    int j0 = (jt & 3) * BM;
    int n1 = cnt1[b];
    if (j0 >= n1) return;

    int r = tid >> 1;
    int koff = (tid & 1) * 16;
    int l = ridx[b * L_ + j0 + r];
    size_t abase = ((size_t)b * L_ + l) * (size_t)H_;
    const float* hrow = hs + abase;
    const float* xrow = xx + abase;
    const float* browf = Wa + (size_t)(n0 + r) * D_;
    const unsigned short* bw0 = Wb ? Wb + (size_t)(n0 + (tid >> 2)) * D_ + (tid & 3) * 8 : nullptr;
    const unsigned short* bw1 = Wb ? Wb + (size_t)(n0 + 64 + (tid >> 2)) * D_ + (tid & 3) * 8 : nullptr;
    unsigned short* bs0 = &Bsl[0][0] + (size_t)tid * 8;
    unsigned short* bs1 = &Bsl[0][0] + (size_t)(tid + 256) * 8;
    bool useWb = (Wb != nullptr);

    f32x4 acc[4][4] = {};

    for (int k0 = 0; k0 < D_; k0 += BK) {
        int k = k0 + koff;
        const float* ap = (k < H_) ? (hrow + k) : (xrow + (k - H_));
        float4 a0 = *(const float4*)(ap);
        float4 a1 = *(const float4*)(ap + 4);
        float4 a2 = *(const float4*)(ap + 8);
        float4 a3 = *(const float4*)(ap + 12);
        uint4 bv0, bv1;
        float4 c0, c1, c2, c3;
        if (useWb) {
            bv0 = *(const uint4*)(bw0 + k0);
            bv1 = *(const uint4*)(bw1 + k0);
        } else {
            const float* bp = browf + k;
            c0 = *(const float4*)(bp);
            c1 = *(const float4*)(bp + 4);
            c2 = *(const float4*)(bp + 8);
            c3 = *(const float4*)(bp + 12);
        }
        __syncthreads();
        *(uint4*)&Asl[r][koff]     = make_uint4(pk(a0.x,a0.y), pk(a0.z,a0.w), pk(a1.x,a1.y), pk(a1.z,a1.w));
        *(uint4*)&Asl[r][koff + 8] = make_uint4(pk(a2.x,a2.y), pk(a2.z,a2.w), pk(a3.x,a3.y), pk(a3.z,a3.w));
        if (useWb) {
            *(uint4*)bs0 = bv0;
            *(uint4*)bs1 = bv1;
        } else {
            *(uint4*)&Bsl[r][koff]     = make_uint4(pk(c0.x,c0.y), pk(c0.z,c0.w), pk(c1.x,c1.y), pk(c1.z,c1.w));
            *(uint4*)&Bsl[r][koff + 8] = make_uint4(pk(c2.x,c2.y), pk(c2.z,c2.w), pk(c3.x,c3.y), pk(c3.z,c3.w));
        }
        __syncthreads();
        int kb = (lane >> 4) * 8;
        short8 af[4], bfg[4];
#pragma unroll
        for (int i = 0; i < 4; ++i) af[i]  = *(const short8*)&Asl[wm*64 + i*16 + (lane & 15)][kb];
#pragma unroll
        for (int j = 0; j < 4; ++j) bfg[j] = *(const short8*)&Bsl[wn*64 + j*16 + (lane & 15)][kb];
#pragma unroll
        for (int i = 0; i < 4; ++i)
#pragma unroll
            for (int j = 0; j < 4; ++j)
                acc[i][j] = __builtin_amdgcn_mfma_f32_16x16x32_bf16(af[i], bfg[j], acc[i][j], 0, 0, 0);
    }

    int cl = lane & 15, qd = lane >> 4;
    float t2v[4]; int ecol[4];
#pragma unroll
    for (int j = 0; j < 4; ++j) { ecol[j] = n0 + wn*64 + j*16 + cl; t2v[j] = t2[b * D_ + ecol[j]]; }
    int orow0 = b * L_ + j0;

    if (mode <= 1) {
        float rs[4][4] = {};
#pragma unroll
        for (int i = 0; i < 4; ++i) {
            int lrowb = wm*64 + i*16 + qd*4;
#pragma unroll
            for (int j = 0; j < 4; ++j) {
#pragma unroll
                for (int g = 0; g < 4; ++g) {
                    float p = fast_pexp(acc[i][j][g] + t2v[j]);
                    rs[i][g] += p;
                    if (mode == 0)
                        P[(size_t)(orow0 + lrowb + g) * D_ + ecol[j]] = f2bf(p);
                }
            }
        }
#pragma unroll
        for (int i = 0; i < 4; ++i)
#pragma unroll
            for (int g = 0; g < 4; ++g) {
                float v = rs[i][g];
                v += __shfl_xor(v, 1); v += __shfl_xor(v, 2);
                v += __shfl_xor(v, 4); v += __shfl_xor(v, 8);
                rs[i][g] = v;
            }
        __syncthreads();
        if (tid < BM) red[tid] = 0.f;
        __syncthreads();
        if (cl == 0) {
#pragma unroll
            for (int i = 0; i < 4; ++i)
#pragma unroll
                for (int g = 0; g < 4; ++g)
                    atomicAdd(&red[wm*64 + i*16 + qd*4 + g], rs[i][g]);
        }
        __syncthreads();
        if (tid < BM) atomicAdd(&rowsum[orow0 + tid], red[tid]);
    } else {
        float inv[4][4];
#pragma unroll
        for (int i = 0; i < 4; ++i)
#pragma unroll
            for (int g = 0; g < 4; ++g) {
                int lrow = wm*64 + i*16 + qd*4 + g;
                inv[i][g] = (j0 + lrow < n1) ? (1.f / rowsum[orow0 + lrow]) : 0.f;
            }
        float cs[4] = {};
#pragma unroll
        for (int i = 0; i < 4; ++i)
#pragma unroll
            for (int j = 0; j < 4; ++j)
#pragma unroll
                for (int g = 0; g < 4; ++g)
                    cs[j] += fast_pexp(acc[i][j][g] + t2v[j]) * inv[i][g];
#pragma unroll
        for (int j = 0; j < 4; ++j) {
            float v = cs[j];
            v += __shfl_xor(v, 16); v += __shfl_xor(v, 32);
            cs[j] = v;
        }
        __syncthreads();
        if (tid < BN) red[tid] = 0.f;
        __syncthreads();
        if (qd == 0) {
#pragma unroll
            for (int j = 0; j < 4; ++j) atomicAdd(&red[wn*64 + j*16 + cl], cs[j]);
        }
        __syncthreads();
        if (tid < BN) atomicAdd(&out[b * D_ + n0 + tid], red[tid]);
    }
}

__global__ __launch_bounds__(256) void k_inv(const int* __restrict__ cnt1,
                                             const float* __restrict__ rowsum,
                                             float* __restrict__ invr) {
    int t = blockIdx.x * 256 + threadIdx.x;
    int b = t >> 9, j = t & 511;
    invr[t] = (j < cnt1[b]) ? (1.f / rowsum[t]) : 0.f;
}

__global__ __launch_bounds__(256) void k_fin(const unsigned short* __restrict__ P,
                                             const float* __restrict__ invr,
                                             const int* __restrict__ cnt1,
                                             float* __restrict__ out) {
    int b = blockIdx.y;
    int lz = blockIdx.z * 128;
    if (lz >= cnt1[b]) return;
    int e0 = blockIdx.x * 512 + threadIdx.x * 2;
    const unsigned short* Pb = P + ((size_t)b * L_ + lz) * D_ + e0;
    const float* ivb = invr + b * L_ + lz;
    float s0 = 0.f, s1 = 0.f;
    for (int l = 0; l < 128; ++l) {
        float iv = ivb[l];
        u32 pv = *(const u32*)(Pb + (size_t)l * D_);
        s0 += iv * bf2f(pv & 0xffffu);
        s1 += iv * bf2f(pv >> 16);
    }
    atomicAdd(&out[b * D_ + e0], s0);
    atomicAdd(&out[b * D_ + e0 + 1], s1);
}

__global__ __launch_bounds__(256) void k_final(
    const float* __restrict__ hs, const float* __restrict__ xx,
    const int* __restrict__ trigger, const float* __restrict__ cnt0,
    float* __restrict__ out) {
    int t = blockIdx.x * 256 + threadIdx.x;
    int b = t >> 11, e = t & 2047;
    int trig = trigger[b];
    size_t base = ((size_t)b * L_ + trig) * 1024;
    float ta = (e < 1024) ? hs[base + e] : xx[base + e - 1024];
    out[t] = (out[t] + cnt0[b] * (1.0f / 2048.0f)) * ta;
}

extern "C" void kernel_launch(void* const* d_in, const int* in_sizes, int n_in,
                              void* d_out, int out_size, void* d_ws, size_t ws_size,
                              hipStream_t stream) {
    const float* hs = (const float*)d_in[0];
    const float* xx = (const float*)d_in[1];
    const float* Wa = (const float*)d_in[2];
    const float* ba = (const float*)d_in[3];
    const float* Ws = (const float*)d_in[4];
    const float* bs = (const float*)d_in[5];
    const int*   trig = (const int*)d_in[6];
    const int*   mask = (const int*)d_in[7];
    float* out = (float*)d_out;

    float* wsf    = (float*)d_ws;
    float* s      = wsf;                 // 65536
    float* t2     = s + 65536;           // 131072
    float* cnt0   = t2 + 131072;         // 64
    float* rowsum = cnt0 + 64;           // 32768
    float* invr   = rowsum + 32768;      // 32768 (v1 only)
    int*   cnt1   = (int*)(invr + 32768);// 64
    int*   ridx   = cnt1 + 64;           // 32768
    unsigned short* P   = (unsigned short*)(ridx + 32768);   // 134,217,728 B @ 1,180,160
    unsigned short* Wb  = P + (size_t)B_ * L_ * D_;          //   8,388,608 B
    unsigned short* Abf = Wb + (size_t)D_ * D_;              // 134,217,728 B

    const size_t BASE_B   = 1180160ull;
    const size_t NEED_P   = BASE_B + 134217728ull;
    const size_t NEED_WB  = NEED_P + 8388608ull;
    const size_t NEED_ALL = NEED_WB + 134217728ull;          // ~278 MB
    bool haveP   = ws_size >= NEED_P;
    bool haveWb  = ws_size >= NEED_WB;
    bool haveAll = ws_size >= NEED_ALL;

    (void)hipMemsetAsync(rowsum, 0, (size_t)B_ * L_ * sizeof(float), stream);

    k_s      <<<256, 256, 0, stream>>>(hs, s);
    k_compact<<<B_, 256, 0, stream>>>(mask, ba, bs, ridx, cnt1, cnt0, t2);
    k_t2     <<<dim3(32, 4), 256, 0, stream>>>(s, Ws, t2);

    dim3 grid(D_ / BN, (B_ * L_) / BM);   // 16 x 256 (blocks past cnt1 self-exit)

    if (haveAll) {
        // v2: all-bf16 GEMM with async global->LDS staging
        k_cvtW <<<4096, 256, 0, stream>>>(Wa, Wb);
        k_prep <<<dim3(512, 64), 256, 0, stream>>>(hs, xx, ridx, cnt1, Abf);
        k_gemm2<<<grid, 256, 0, stream>>>(Abf, Wb, t2, cnt1, rowsum, P);
        k_fin2 <<<dim3(4, 64), 256, 0, stream>>>(P, rowsum, cnt1, trig, hs, xx, out);
    } else {
        const unsigned short* WbArg = haveWb ? Wb : nullptr;
        if (haveWb) k_cvtW<<<4096, 256, 0, stream>>>(Wa, Wb);
        (void)hipMemsetAsync(out, 0, (size_t)B_ * D_ * sizeof(float), stream);
        if (haveP) {
            k_gemm<<<grid, 256, 0, stream>>>(hs, xx, Wa, WbArg, t2, ridx, cnt1, rowsum, P, out, 0);
            k_inv <<<(B_ * L_) / 256, 256, 0, stream>>>(cnt1, rowsum, invr);
            k_fin <<<dim3(4, 64, 4), 256, 0, stream>>>(P, invr, cnt1, out);
        } else {
            k_gemm<<<grid, 256, 0, stream>>>(hs, xx, Wa, WbArg, t2, ridx, cnt1, rowsum, P, out, 1);
            k_gemm<<<grid, 256, 0, stream>>>(hs, xx, Wa, WbArg, t2, ridx, cnt1, rowsum, P, out, 2);
        }
        k_final<<<(B_ * D_) / 256, 256, 0, stream>>>(hs, xx, trig, cnt0, out);
    }
}